// Round 12
// baseline (6471.029 us; speedup 1.0000x reference)
//
#include <hip/hip_runtime.h>

#define T_ 256
#define B_ 128
#define I_ 1024
#define H_ 1024
#define G_ 4096   // 4*H
#define BH (B_*H_)   // 131072
#define TB (T_*B_)   // 32768

typedef float f32x4 __attribute__((ext_vector_type(4)));
typedef short bf16x8 __attribute__((ext_vector_type(8)));
typedef int   i32x4  __attribute__((ext_vector_type(4)));

__device__ inline unsigned short f2bf(float f) {
    union { float f; unsigned int u; } v; v.f = f;
    unsigned int u = v.u;
    unsigned int r = (u + 0x7fffu + ((u >> 16) & 1u)) >> 16;
    return (unsigned short)r;
}
__device__ inline float bf2f(unsigned short s) {
    union { unsigned int u; float f; } v; v.u = ((unsigned int)s) << 16;
    return v.f;
}
__device__ inline float sigmoidf_(float x) { return 1.0f / (1.0f + __expf(-x)); }
__device__ inline float tanhf_(float x) {
    x = fminf(15.0f, fmaxf(-15.0f, x));
    float e = __expf(2.0f * x);
    return (e - 1.0f) / (e + 1.0f);
}

// ---------------- convert fp32 -> bf16 (vectorized) ----------------
__global__ void cvt_kernel(const float* __restrict__ src, unsigned short* __restrict__ dst, int n) {
    int i = (blockIdx.x * blockDim.x + threadIdx.x) * 4;
    int stride = gridDim.x * blockDim.x * 4;
    for (; i < n; i += stride) {
        float4 v = *reinterpret_cast<const float4*>(src + i);
        ushort4 o;
        o.x = f2bf(v.x); o.y = f2bf(v.y); o.z = f2bf(v.z); o.w = f2bf(v.w);
        *reinterpret_cast<ushort4*>(dst + i) = o;
    }
}

// h0 -> bf16 with tag bit0 = 0 (generation 0)
__global__ void cvt_h0_kernel(const float* __restrict__ src, unsigned short* __restrict__ dst, int n) {
    int i = (blockIdx.x * blockDim.x + threadIdx.x) * 4;
    int stride = gridDim.x * blockDim.x * 4;
    for (; i < n; i += stride) {
        float4 v = *reinterpret_cast<const float4*>(src + i);
        ushort4 o;
        o.x = f2bf(v.x) & 0xFFFE; o.y = f2bf(v.y) & 0xFFFE;
        o.z = f2bf(v.z) & 0xFFFE; o.w = f2bf(v.w) & 0xFFFE;
        *reinterpret_cast<ushort4*>(dst + i) = o;
    }
}

// buf1 init: tag-1 filler (0x0001 per bf16)
__global__ void init_b1_kernel(unsigned* __restrict__ p) {
    int i = (blockIdx.x * blockDim.x + threadIdx.x) * 4;
    i32x4 v = {0x00010001, 0x00010001, 0x00010001, 0x00010001};
    *reinterpret_cast<i32x4*>(p + i) = v;
}

__global__ void bias_kernel(const float* __restrict__ a, const float* __restrict__ b, float* __restrict__ out) {
    int i = blockIdx.x * blockDim.x + threadIdx.x;
    if (i < G_) out[i] = a[i] + b[i];
}

// ---------------- fused persistent kernel: pregemm-per-step + recurrence ----------------
// r11 sync (tag-in-data h exchange, proven). NEW: gx computed just-in-time,
// block-locally: while step t's gates settle, each block computes its own
// gx(t+1) slice (x rows: plain cached loads; Wih frags: L2; same MFMA layout)
// into a second LDS buffer. No pregemm dispatch, no 512 MB gx HBM stream.
__global__ __launch_bounds__(512) void lstm_recur(
    const unsigned short* __restrict__ whh,   // [4096][1024] bf16
    const unsigned short* __restrict__ wih,   // [4096][1024] bf16
    const unsigned short* __restrict__ xb,    // [32768][1024] bf16
    const float* __restrict__ bias,           // [4096] = b_ih + b_hh
    const float* __restrict__ c0,             // [128][1024]
    unsigned short* __restrict__ hbuf,        // [2][128][1024] bf16 (buf0=h0 tag0, buf1=tag1 filler)
    float* __restrict__ ys,
    float* __restrict__ hT, float* __restrict__ cT)
{
    __shared__ unsigned short whh_lds[8192 * 8];   // 128 KB: [ck][row][8]
    __shared__ float lds_g[4][32][16];             // 8 KB: h-gates accumulator
    __shared__ float lds_gx[4][32][16];            // 8 KB: gx accumulator

    const int bid = blockIdx.x;
    const int mg  = (bid & 7) >> 1;
    const int ing = (bid >> 3) * 2 + (bid & 1);
    const int m0 = mg * 32, n0 = ing * 16;

    const int tid = threadIdx.x;
    const int w = tid >> 6, l = tid & 63;
    const int mh = w >> 2, kq = w & 3;
    const int lr = l & 15, lkidx = l >> 4;

    // ---- stage Whh slice into LDS once (k-major, r5-verified) ----
    for (int it = 0; it < 16; ++it) {
        int idx = it * 512 + tid;
        int row = idx >> 7;
        int ck  = idx & 127;
        int gg = row >> 4, cc = row & 15;
        bf16x8 v = *reinterpret_cast<const bf16x8*>(
            whh + (size_t)(gg * 1024 + n0 + cc) * H_ + ck * 8);
        *reinterpret_cast<bf16x8*>(whh_lds + ((size_t)ck * 64 + row) * 8) = v;
    }
    // zero lds_gx for prologue accumulation
    {
        float* lgx = (float*)lds_gx;
        lgx[tid] = 0.f; lgx[tid + 512] = 0.f; lgx[tid + 1024] = 0.f; lgx[tid + 1536] = 0.f;
    }
    __syncthreads();

    const unsigned short* bwave = whh_lds + (((size_t)(kq * 32 + lkidx)) * 64 + lr) * 8;

    const int erow = tid >> 4, ecol = tid & 15;
    const size_t eoff = (size_t)(m0 + erow) * H_ + n0 + ecol;
    float c = c0[eoff];
    const float bias_i = bias[n0 + ecol];
    const float bias_f = bias[1024 + n0 + ecol];
    const float bias_g = bias[2048 + n0 + ecol];
    const float bias_o = bias[3072 + n0 + ecol];

    const size_t hrow = (size_t)(m0 + mh * 16 + lr) * H_ + kq * 256;
    // Wih fragment base for this wave/lane (gate g4 adds g4*1024 rows)
    const unsigned short* wihb_g = wih + (size_t)(n0 + lr) * I_ + kq * 256 + lkidx * 8;

    bf16x8 ax[8];
    f32x4 accx[4];

    // x-frag loads for time TT (plain cached; rows = this block/wave's batch rows)
#define XLOAD(TT)                                                                   \
    {                                                                               \
        const unsigned short* xp = xb                                               \
            + (size_t)((TT) * B_ + m0 + mh * 16 + lr) * I_ + kq * 256 + lkidx * 8;  \
        _Pragma("unroll")                                                           \
        for (int kk = 0; kk < 8; ++kk)                                              \
            ax[kk] = *reinterpret_cast<const bf16x8*>(xp + kk * 32);                \
    }
    // gx partials: 4 gates x this wave's k-quarter (Wih frags from L2)
#define XGEMM()                                                                     \
    {                                                                               \
        _Pragma("unroll")                                                           \
        for (int g4 = 0; g4 < 4; ++g4) {                                            \
            const unsigned short* wp = wihb_g + (size_t)g4 * 1024 * I_;             \
            bf16x8 bw[8];                                                           \
            _Pragma("unroll")                                                       \
            for (int kk = 0; kk < 8; ++kk)                                          \
                bw[kk] = *reinterpret_cast<const bf16x8*>(wp + kk * 32);            \
            accx[g4] = (f32x4){0.f, 0.f, 0.f, 0.f};                                 \
            _Pragma("unroll")                                                       \
            for (int kk = 0; kk < 8; ++kk)                                          \
                accx[g4] = __builtin_amdgcn_mfma_f32_16x16x32_bf16(                 \
                    ax[kk], bw[kk], accx[g4], 0, 0, 0);                             \
        }                                                                           \
    }
#define XADD()                                                                      \
    {                                                                               \
        _Pragma("unroll")                                                           \
        for (int g4 = 0; g4 < 4; ++g4)                                              \
            _Pragma("unroll")                                                       \
            for (int r = 0; r < 4; ++r)                                             \
                atomicAdd(&lds_gx[g4][mh * 16 + lkidx * 4 + r][lr], accx[g4][r]);   \
    }

    // ---- prologue: gx(0) ----
    XLOAD(0)
    XGEMM()
    XADD()

    for (int t = 0; t < T_; ++t) {
        // issue next step's x loads early (latency hides under the h poll)
        if (t + 1 < T_) XLOAD(t + 1)

        // ---- tag-poll + load h(t): all 32 dwords must carry tag (t>>1)&1 ----
        const char* hpb = (const char*)hbuf
            + ((size_t)(t & 1) * BH + hrow) * 2 + lkidx * 16;
        const unsigned expw = ((unsigned)((t >> 1) & 1)) * 0x00010001u;
        i32x4 hv0, hv1, hv2, hv3, hv4, hv5, hv6, hv7;
        while (true) {
            asm volatile("global_load_dwordx4 %0, %1, off sc0 sc1"             : "=&v"(hv0) : "v"(hpb));
            asm volatile("global_load_dwordx4 %0, %1, off offset:64 sc0 sc1"   : "=&v"(hv1) : "v"(hpb));
            asm volatile("global_load_dwordx4 %0, %1, off offset:128 sc0 sc1"  : "=&v"(hv2) : "v"(hpb));
            asm volatile("global_load_dwordx4 %0, %1, off offset:192 sc0 sc1"  : "=&v"(hv3) : "v"(hpb));
            asm volatile("global_load_dwordx4 %0, %1, off offset:256 sc0 sc1"  : "=&v"(hv4) : "v"(hpb));
            asm volatile("global_load_dwordx4 %0, %1, off offset:320 sc0 sc1"  : "=&v"(hv5) : "v"(hpb));
            asm volatile("global_load_dwordx4 %0, %1, off offset:384 sc0 sc1"  : "=&v"(hv6) : "v"(hpb));
            asm volatile("global_load_dwordx4 %0, %1, off offset:448 sc0 sc1"  : "=&v"(hv7) : "v"(hpb));
            asm volatile("s_waitcnt vmcnt(0)" ::: "memory");
            __builtin_amdgcn_sched_barrier(0);
            unsigned bad = 0;
#define CHK(HV) bad |= (((unsigned)HV[0] ^ expw) | ((unsigned)HV[1] ^ expw) | \
                        ((unsigned)HV[2] ^ expw) | ((unsigned)HV[3] ^ expw)) & 0x00010001u;
            CHK(hv0) CHK(hv1) CHK(hv2) CHK(hv3) CHK(hv4) CHK(hv5) CHK(hv6) CHK(hv7)
#undef CHK
            if (__all((int)(bad == 0))) break;
            __builtin_amdgcn_s_sleep(2);
        }

        // zero h-gate accumulators
        {
            float* lg = (float*)lds_g;
            lg[tid] = 0.f; lg[tid + 512] = 0.f; lg[tid + 1024] = 0.f; lg[tid + 1536] = 0.f;
        }

        // ---- h-MFMA: partials for all 4 gates over this wave's k-quarter ----
        f32x4 acc[4] = {};
#define MFMA_K(KK, HV)                                                              \
        {                                                                           \
            bf16x8 av = __builtin_bit_cast(bf16x8, HV);                             \
            _Pragma("unroll")                                                       \
            for (int g4 = 0; g4 < 4; ++g4) {                                        \
                bf16x8 bb = *reinterpret_cast<const bf16x8*>(                       \
                    bwave + (KK) * 2048 + g4 * 128);                                \
                acc[g4] = __builtin_amdgcn_mfma_f32_16x16x32_bf16(                  \
                    av, bb, acc[g4], 0, 0, 0);                                      \
            }                                                                       \
        }
        MFMA_K(0, hv0) MFMA_K(1, hv1) MFMA_K(2, hv2) MFMA_K(3, hv3)
        MFMA_K(4, hv4) MFMA_K(5, hv5) MFMA_K(6, hv6) MFMA_K(7, hv7)
#undef MFMA_K
        __syncthreads();   // (d) zeros visible before ds_add

        #pragma unroll
        for (int g4 = 0; g4 < 4; ++g4)
            #pragma unroll
            for (int r = 0; r < 4; ++r)
                atomicAdd(&lds_g[g4][mh * 16 + lkidx * 4 + r][lr], acc[g4][r]);

        // ---- gx(t+1) partials while gate sums settle ----
        if (t + 1 < T_) XGEMM()

        __syncthreads();   // (f) gate sums + gx(t) complete

        // ---- fused elementwise: gates = Whh part + x part + bias ----
        float gi = lds_g[0][erow][ecol] + lds_gx[0][erow][ecol] + bias_i;
        float gf = lds_g[1][erow][ecol] + lds_gx[1][erow][ecol] + bias_f;
        float gg = lds_g[2][erow][ecol] + lds_gx[2][erow][ecol] + bias_g;
        float go = lds_g[3][erow][ecol] + lds_gx[3][erow][ecol] + bias_o;
        float iv = sigmoidf_(gi);
        float fv = sigmoidf_(gf);
        float gv = tanhf_(gg);
        float ov = sigmoidf_(go);
        c = fv * c + iv * gv;
        float hn = ov * tanhf_(c);

        // h store with generation tag in bit0 (fire-and-forget, proven path)
        {
            const unsigned wtag = ((unsigned)(t + 1) >> 1) & 1u;
            unsigned us0 = ((unsigned)f2bf(hn) & 0xFFFEu) | wtag;
            float hn_o = __shfl_xor(hn, 1);
            unsigned us1 = ((unsigned)f2bf(hn_o) & 0xFFFEu) | wtag;
            if ((tid & 1) == 0) {
                unsigned u = us0 | (us1 << 16);
                unsigned short* hbn = hbuf + (size_t)((t + 1) & 1) * BH;
                __hip_atomic_store((unsigned*)(hbn + eoff), u,
                                   __ATOMIC_RELAXED, __HIP_MEMORY_SCOPE_AGENT);
            }
        }
        ys[(size_t)t * BH + eoff] = hn;
        if (t == T_ - 1) { hT[eoff] = hn; cT[eoff] = c; }

        __syncthreads();   // (h) lds_gx reads done

        if (t + 1 < T_) {
            float* lgx = (float*)lds_gx;
            lgx[tid] = 0.f; lgx[tid + 512] = 0.f; lgx[tid + 1024] = 0.f; lgx[tid + 1536] = 0.f;
        }
        __syncthreads();   // (j) zeros visible

        if (t + 1 < T_) XADD()
        // (next iteration's sync (d)/(f) orders these adds before their read)
    }
#undef XLOAD
#undef XGEMM
#undef XADD
}

extern "C" void kernel_launch(void* const* d_in, const int* in_sizes, int n_in,
                              void* d_out, int out_size, void* d_ws, size_t ws_size,
                              hipStream_t stream)
{
    const float* x   = (const float*)d_in[0];
    const float* h0  = (const float*)d_in[1];
    const float* c0  = (const float*)d_in[2];
    const float* Wih = (const float*)d_in[3];
    const float* Whh = (const float*)d_in[4];
    const float* bih = (const float*)d_in[5];
    const float* bhh = (const float*)d_in[6];

    // workspace layout (bytes)
    char* ws = (char*)d_ws;
    unsigned short* xb   = (unsigned short*)(ws);                 //  64 MB x bf16
    unsigned short* wihb = (unsigned short*)(ws + 67108864);      //   8 MB Wih bf16
    unsigned short* whhb = (unsigned short*)(ws + 75497472);      //   8 MB Whh bf16
    unsigned short* hbuf = (unsigned short*)(ws + 83886080);      // 512 KB h dbuf bf16 (tagged)
    float*          bias = (float*)(ws + 84410368);               //  16 KB

    float* out = (float*)d_out;
    float* ys = out;                           // [256][128][1024]
    float* hT = out + (size_t)TB * H_;         // [128][1024]
    float* cT = hT + BH;                       // [128][1024]

    cvt_kernel<<<2048, 256, 0, stream>>>(x,   xb,   TB * I_);
    cvt_kernel<<<512,  256, 0, stream>>>(Wih, wihb, G_ * I_);
    cvt_kernel<<<512,  256, 0, stream>>>(Whh, whhb, G_ * H_);
    cvt_h0_kernel<<<128, 256, 0, stream>>>(h0, hbuf, BH);           // buf0 = h0, tag 0
    init_b1_kernel<<<64, 256, 0, stream>>>((unsigned*)(hbuf + BH)); // buf1 = tag-1 filler
    bias_kernel<<<16, 256, 0, stream>>>(bih, bhh, bias);

    lstm_recur<<<256, 512, 0, stream>>>(whhb, wihb, xb, bias, c0, hbuf, ys, hT, cT);
}